// Round 1
// baseline (9.655 us; speedup 1.0000x reference)
//
#include <hip/hip_runtime.h>

// SSD PriorBox generation.
// 6 layers, shapes (lw,lh) in d_in[4] (int32 pairs), K = 2+len(ars) boxes/cell.
// AR_SEL = {0,1,1,1,0,0}: layers 0,4,5 use ar2 (K=4), layers 1,2,3 use ar4 (K=6).
// Total boxes = sum lw*lh*K = 8732; out = 8732 x 4 fp32 (xmin,ymin,xmax,ymax).
// Box order: layer-major, cell row-major (i over lh, j over lw), then k.

__global__ void prior_box_kernel(const float* __restrict__ min_sizes,
                                 const float* __restrict__ max_sizes,
                                 const float* __restrict__ ar2,
                                 const float* __restrict__ ar4,
                                 const int*   __restrict__ shapes,
                                 float*       __restrict__ out,
                                 int n_boxes) {
    int idx = blockIdx.x * blockDim.x + threadIdx.x;
    if (idx >= n_boxes) return;

    // AR_SEL as a compile-time constant (per the reference's Python constant).
    const int arsel0 = 0, arsel1 = 1, arsel2 = 1, arsel3 = 1, arsel4 = 0, arsel5 = 0;
    const int arsel[6] = {arsel0, arsel1, arsel2, arsel3, arsel4, arsel5};

    // Locate (layer L, local index rem) via prefix walk over layer box counts.
    int rem = idx;
    int L = 0, lw = 1, lh = 1, K = 4;
    #pragma unroll
    for (int t = 0; t < 6; ++t) {
        if (t < L) continue;           // keep unrolled structure simple
        lw = shapes[2 * t + 0];
        lh = shapes[2 * t + 1];
        K  = arsel[t] ? 6 : 4;
        int cnt = lw * lh * K;
        if (rem < cnt) { L = t; break; }
        rem -= cnt;
        L = t + 1;
    }

    int cell = rem / K;
    int k    = rem - cell * K;
    int i    = cell / lw;              // row index (over lh)
    int j    = cell - i * lw;          // col index (over lw)

    // Reference: cx = (j+0.5)*(IMG_W/lh); cy = (i+0.5)*(IMG_H/lw)  (crossed divisors)
    float cx = ((float)j + 0.5f) * (300.0f / (float)lh);
    float cy = ((float)i + 0.5f) * (300.0f / (float)lw);

    float ms = min_sizes[L];
    float w, h;
    if (k == 0) {
        w = ms; h = ms;
    } else if (k == 1) {
        float g = sqrtf(ms * max_sizes[L]);
        w = g; h = g;
    } else {
        const float* ars = arsel[L] ? ar4 : ar2;
        float a  = ars[k - 2];
        float sa = sqrtf(a);
        w = ms * sa;
        h = ms / sa;
    }

    const float inv = 1.0f / 300.0f;
    float x0 = (cx - 0.5f * w) * inv;
    float y0 = (cy - 0.5f * h) * inv;
    float x1 = (cx + 0.5f * w) * inv;
    float y1 = (cy + 0.5f * h) * inv;

    x0 = fminf(fmaxf(x0, 0.0f), 1.0f);
    y0 = fminf(fmaxf(y0, 0.0f), 1.0f);
    x1 = fminf(fmaxf(x1, 0.0f), 1.0f);
    y1 = fminf(fmaxf(y1, 0.0f), 1.0f);

    reinterpret_cast<float4*>(out)[idx] = make_float4(x0, y0, x1, y1);
}

extern "C" void kernel_launch(void* const* d_in, const int* in_sizes, int n_in,
                              void* d_out, int out_size, void* d_ws, size_t ws_size,
                              hipStream_t stream) {
    const float* min_sizes = (const float*)d_in[0];
    const float* max_sizes = (const float*)d_in[1];
    const float* ar2       = (const float*)d_in[2];
    const float* ar4       = (const float*)d_in[3];
    const int*   shapes    = (const int*)d_in[4];
    float* out = (float*)d_out;

    int n_boxes = out_size / 4;        // 8732
    int block = 256;
    int grid = (n_boxes + block - 1) / block;
    prior_box_kernel<<<grid, block, 0, stream>>>(min_sizes, max_sizes, ar2, ar4,
                                                 shapes, out, n_boxes);
}